// Round 9
// baseline (257.154 us; speedup 1.0000x reference)
//
#include <hip/hip_runtime.h>

// ChebyKANLayer: y[t,o] = bias[o] + sum_k A[t,k]*B[k,o], K=8192, k=i*8+(d-1), d=1..8.
// R15: prep de-bottlenecked. th2 is ROW-MAJOR permuted tanh (R11-verified math):
// th-gen becomes a pure streaming kernel (coalesced f32x4 in/out, no LDS, no sync).
// Gemm consumes it via per-lane-source g2lds (dest linear): LDS seed image [row][32B],
// one ds_read_b128 at row*32+h*16 = the lane's 4 seeds (pos=h*4+ks -> li=h+2ks).
// Gemm otherwise byte-identical to R14's verified kernel (152us, MfmaUtil 42.6).

typedef __bf16 bf16;
typedef __bf16 bf16x8 __attribute__((ext_vector_type(8)));
typedef float f32x2 __attribute__((ext_vector_type(2)));
typedef float f32x4 __attribute__((ext_vector_type(4)));
typedef float f32x16 __attribute__((ext_vector_type(16)));

#define MFMA __builtin_amdgcn_mfma_f32_32x32x16_bf16

__device__ __forceinline__ void g2lds16(const void* g, void* l) {
  __builtin_amdgcn_global_load_lds(
      (const __attribute__((address_space(1))) unsigned int*)g,
      (__attribute__((address_space(3))) unsigned int*)l, 16, 0, 0);
}

__device__ __forceinline__ float fast_tanh(float a) {
  float e = __expf(a + a);
  return 1.f - 2.f * __builtin_amdgcn_rcpf(e + 1.f);   // saturating, NaN-free
}

// ============================ FUSED PREP ============================
// bid < 4096: th2 stream. th2[r][t*8+pos] = tanh(x[r][t*8+li]), pos=(li&1)*4+(li>>1)
//   (R11-verified permutation; even li -> pos 0..3, odd li -> pos 4..7).
// bid >= 4096: B repack + bias partials (verified unchanged).
//   B: [nb 0..7][kt 0..127][8192 bf16], elem (((ks*4+n32)*2+h)*32+o31)*8 + (d-1),
//   i = kt*8 + 2ks + h.  bias_p[p][o] = sum_{i in 32-block p} C[i][o][0].
__global__ __launch_bounds__(256)
void cheby_prep7(const float* __restrict__ x, const float* __restrict__ C,
                 bf16* __restrict__ B, float* __restrict__ bias_p,
                 float* __restrict__ th2) {
  const int bid = blockIdx.x, tid = threadIdx.x;
  if (bid < 4096) {                                  // ---- th stream: one 8-group/thread
    const size_t g = (size_t)bid * 256 + tid;        // 1,048,576 groups
    const float* xp = x + g * 8;
    f32x4 a  = *(const f32x4*)(xp);
    f32x4 b4 = *(const f32x4*)(xp + 4);
    f32x4 e = { fast_tanh(a.x), fast_tanh(a.z), fast_tanh(b4.x), fast_tanh(b4.z) };
    f32x4 o = { fast_tanh(a.y), fast_tanh(a.w), fast_tanh(b4.y), fast_tanh(b4.w) };
    float* dp = th2 + g * 8;
    *(f32x4*)dp       = e;                           // pos 0..3 (li = 0,2,4,6)
    *(f32x4*)(dp + 4) = o;                           // pos 4..7 (li = 1,3,5,7)
    return;
  }
  const int b2 = bid - 4096;
  __shared__ float tile[32][292];
  const int i0 = (b2 >> 5) * 32, o0 = (b2 & 31) * 32;
  {
    const int r = tid >> 3, seg = tid & 7;
    const float* src = C + (size_t)(i0 + r) * 9216 + (size_t)o0 * 9 + seg * 36;
    float* dst = &tile[r][seg * 36];
    #pragma unroll
    for (int v = 0; v < 9; ++v) *(f32x4*)(dst + v * 4) = *(const f32x4*)(src + v * 4);
  }
  __syncthreads();
  #pragma unroll
  for (int j = 0; j < 4; ++j) {
    int e = tid + 256 * j;
    int il = e >> 5, ol = e & 31;
    int i = i0 + il, o = o0 + ol;
    bf16x8 v;
    #pragma unroll
    for (int d = 0; d < 8; ++d) v[d] = (bf16)tile[il][ol * 9 + 1 + d];
    const int cc = i & 7;
    size_t tnum = (size_t)(o >> 7) * 128 + (i >> 3);
    const int widx = (((cc >> 1) * 4 + ((o & 127) >> 5)) * 2 + (cc & 1)) * 32 + (o & 31);
    *(bf16x8*)(B + tnum * 8192 + widx * 8) = v;
  }
  if (tid < 32) {
    float s = 0.f;
    #pragma unroll
    for (int i = 0; i < 32; ++i) s += tile[i][tid * 9];
    bias_p[(size_t)(b2 >> 5) * 1024 + o0 + tid] = s;
  }
}

// ============================ GEMM (R14 verified; row-major seed slab) ============================
// Block 128x128, 256 thr, 4 waves (2M x 2N), wave 64x64, BK=64, 128 K-steps, 2 blk/CU.
// Ring[3] x 20KB: [0,8192) B image (bf16), byte [16384,20480) seed slab [row 0..127][32B].
// Seed g2lds: per-lane global src (row = tid>>1, half = tid&1), linear LDS dest.
// 5 g2lds/step, prefetch distance 2, counted vmcnt(5), one barrier/step.
__global__ __launch_bounds__(256, 2)
void cheby_gemm10(const float* __restrict__ th2, const bf16* __restrict__ B,
                  const float* __restrict__ bias_p, float* __restrict__ out) {
  __shared__ bf16 ring[3][10240];                    // 3 x 20 KB = 60 KB
  const int tid = threadIdx.x;
  const int lane = tid & 63, w = tid >> 6;
  const int wm = w >> 1, wn = w & 1;
  const int bid = blockIdx.x;
  const int wgid = (bid & 7) * 64 + (bid >> 3);      // XCD-chunked, bijective (512 = 8*64)
  const int mt = wgid >> 3, nb = wgid & 7;

  const int ml = lane & 31, h = lane >> 5;
  const int bBase = wn * 1024 + h * 256 + ml * 8;    // + ks*2048, + nt*512
  const int sB = (wm * 64 + ml) * 8 + h * 4;         // f32 idx into seed slab; +256 row+32

  const bf16*  bG = B + (size_t)nb * 1048576 + tid * 8;
  const float* tG = th2 + (size_t)(mt * 128 + (tid >> 1)) * 1024 + (tid & 1) * 4;

  f32x16 acc[2][2];
  #pragma unroll
  for (int a = 0; a < 2; ++a)
    #pragma unroll
    for (int b = 0; b < 2; ++b)
      #pragma unroll
      for (int r = 0; r < 16; ++r) acc[a][b][r] = 0.f;

  auto issue5 = [&](int t, int p) {
    #pragma unroll
    for (int c = 0; c < 4; ++c)
      g2lds16(bG + (size_t)t * 8192 + c * 2048, &ring[p][c * 2048 + tid * 8]);
    g2lds16(tG + t * 8, &ring[p][8192 + tid * 8]);   // seed slab: lane's own 16B
  };

  issue5(0, 0); issue5(1, 1);
  asm volatile("s_waitcnt vmcnt(5)" ::: "memory");
  __builtin_amdgcn_s_barrier();

  auto step = [&](int t, int pC, int pN) {
    if (t + 2 < 128) issue5(t + 2, pN);              // pN=(t+2)%3: dead since end of t-1
    const bf16* ra = &ring[pC][0];
    const float* seedL = (const float*)(ra + 8192);
    bf16x8 bfr[2][4], afr[2][4];                     // step-local (spill-safe, R12 form)
    #pragma unroll
    for (int ks = 0; ks < 4; ++ks) {
      bfr[0][ks] = *(const bf16x8*)(ra + bBase + ks * 2048);
      bfr[1][ks] = *(const bf16x8*)(ra + bBase + ks * 2048 + 512);
    }
    f32x4 s0 = *(const f32x4*)(seedL + sB);          // rows wm*64+ml : ks 0..3 (this h)
    f32x4 s1 = *(const f32x4*)(seedL + sB + 256);    // rows +32
    #pragma unroll
    for (int ks = 0; ks < 4; ++ks) {                 // verified Chebyshev chain
      f32x2 tv = { s0[ks], s1[ks] };
      f32x2 t2 = tv + tv;
      f32x2 prev = {1.f, 1.f}, cur = tv;
      #pragma unroll
      for (int j = 0; j < 8; ++j) {
        afr[0][ks][j] = (bf16)cur.x;
        afr[1][ks][j] = (bf16)cur.y;
        f32x2 nx = t2 * cur - prev;
        prev = cur; cur = nx;
      }
    }
    __builtin_amdgcn_s_setprio(1);
    #pragma unroll
    for (int ks = 0; ks < 4; ++ks) {
      acc[0][0] = MFMA(afr[0][ks], bfr[0][ks], acc[0][0], 0, 0, 0);
      acc[0][1] = MFMA(afr[0][ks], bfr[1][ks], acc[0][1], 0, 0, 0);
      acc[1][0] = MFMA(afr[1][ks], bfr[0][ks], acc[1][0], 0, 0, 0);
      acc[1][1] = MFMA(afr[1][ks], bfr[1][ks], acc[1][1], 0, 0, 0);
    }
    __builtin_amdgcn_s_setprio(0);
    asm volatile("s_waitcnt lgkmcnt(0)" ::: "memory");   // pC reads done before barrier
    if (t <= 125) asm volatile("s_waitcnt vmcnt(5)" ::: "memory");  // batch(t+1) landed
    else          asm volatile("s_waitcnt vmcnt(0)" ::: "memory");
    __builtin_amdgcn_s_barrier();
  };

  #pragma unroll 1
  for (int t3 = 0; t3 < 126; t3 += 3) {              // static ring indices, t = 0..125
    step(t3,     0, 2);
    step(t3 + 1, 1, 0);
    step(t3 + 2, 2, 1);
  }
  step(126, 0, 2);                                   // no issue (t+2 >= 128)
  step(127, 1, 0);                                   // no issue

  // epilogue: C/D layout col=lane&31, row=(r&3)+8*(r>>2)+4*h (verified)
  const int c0 = nb * 128 + wn * 64 + ml;
  float bv0 = 0.f, bv1 = 0.f;
  #pragma unroll
  for (int p = 0; p < 32; ++p) {
    bv0 += bias_p[(size_t)p * 1024 + c0];
    bv1 += bias_p[(size_t)p * 1024 + c0 + 32];
  }
  const int r0 = mt * 128 + wm * 64;
  #pragma unroll
  for (int mtt = 0; mtt < 2; ++mtt)
    #pragma unroll
    for (int r = 0; r < 16; ++r) {
      int row = r0 + mtt * 32 + (r & 3) + 8 * (r >> 2) + 4 * h;
      float* po = out + (size_t)row * 1024 + c0;
      po[0]  = acc[mtt][0][r] + bv0;
      po[32] = acc[mtt][1][r] + bv1;
    }
}

// ---- naive fallback (ws too small) — correct, slow, should never run
__global__ __launch_bounds__(256)
void cheby_naive(const float* __restrict__ x, const float* __restrict__ C,
                 float* __restrict__ out) {
  const int t = blockIdx.x, tid = threadIdx.x;
  float acc[4] = {0.f, 0.f, 0.f, 0.f};
  for (int i = 0; i < 1024; ++i) {
    float th = tanhf(x[(size_t)t * 1024 + i]);
    float T[9]; T[0] = 1.f; T[1] = th;
    #pragma unroll
    for (int d = 2; d < 9; ++d) T[d] = 2.f * th * T[d - 1] - T[d - 2];
    #pragma unroll
    for (int j = 0; j < 4; ++j) {
      const float* cp = &C[((size_t)i * 1024 + tid + j * 256) * 9];
      float s = 0.f;
      #pragma unroll
      for (int d = 0; d < 9; ++d) s += T[d] * cp[d];
      acc[j] += s;
    }
  }
  #pragma unroll
  for (int j = 0; j < 4; ++j) out[(size_t)t * 1024 + tid + j * 256] = acc[j];
}

extern "C" void kernel_launch(void* const* d_in, const int* in_sizes, int n_in,
                              void* d_out, int out_size, void* d_ws, size_t ws_size,
                              hipStream_t stream) {
  (void)in_sizes; (void)n_in; (void)out_size;
  const float* x = (const float*)d_in[0];
  const float* C = (const float*)d_in[1];
  float* out = (float*)d_out;

  const size_t b_bytes  = (size_t)8 * 128 * 8192 * 2;     // 16.78 MB
  const size_t bp_bytes = (size_t)32 * 1024 * 4;          // 128 KB
  const size_t th_bytes = (size_t)8192 * 1024 * 4;        // 33.55 MB

  if (ws_size >= b_bytes + bp_bytes + th_bytes) {
    bf16*  B      = (bf16*)d_ws;
    float* bias_p = (float*)((char*)d_ws + b_bytes);
    float* th2    = (float*)((char*)d_ws + b_bytes + bp_bytes);
    cheby_prep7<<<5120, 256, 0, stream>>>(x, C, B, bias_p, th2);
    cheby_gemm10<<<512, 256, 0, stream>>>(th2, B, bias_p, out);
  } else {
    cheby_naive<<<8192, 256, 0, stream>>>(x, C, out);
  }
}